// Round 3
// baseline (691.940 us; speedup 1.0000x reference)
//
#include <hip/hip_runtime.h>
#include <hip/hip_bf16.h>

typedef __bf16 bf16;
typedef __attribute__((ext_vector_type(8))) __bf16 bf16x8;
typedef __attribute__((ext_vector_type(4))) __bf16 bf16x4;
typedef __attribute__((ext_vector_type(4))) float f32x4;
typedef __attribute__((ext_vector_type(4))) int i32x4;
typedef unsigned long long u64;

constexpr int SLEN = 2048;
constexpr int DH = 64;
constexpr int NBH = 64;                      // B*H = 4*16
constexpr float SCALE_LOG2E = 0.125f * 1.4426950408889634f;  // (1/sqrt(64)) * log2(e)

// ---- pre-pass 0: mask int32 -> 1 bit, windowed-interleaved format ----
// Window t covers ints [256t, 256t+256); out word[4t+i] bit l = (mask[256t+4l+i] != 0).
// Rows are 2048 ints (multiple of 256), so windows never straddle rows.
// Pure stream: 1.074 GB read @ ~BW, 33.5 MB written.
__global__ __launch_bounds__(256) void pack_mask_kernel(const int* __restrict__ m,
                                                        u64* __restrict__ out) {
    const int l = threadIdx.x & 63;
    const size_t wid = ((size_t)blockIdx.x * blockDim.x + threadIdx.x) >> 6;
    #pragma unroll 4
    for (int it = 0; it < 128; ++it) {           // 8192 waves * 128 = 1,048,576 windows
        size_t t = wid + (size_t)it * 8192;
        i32x4 v = __builtin_nontemporal_load((const i32x4*)m + t * 64 + l);
        u64 b0 = __ballot(v[0] != 0);
        u64 b1 = __ballot(v[1] != 0);
        u64 b2 = __ballot(v[2] != 0);
        u64 b3 = __ballot(v[3] != 0);
        if (l < 4) {
            u64 b = l == 0 ? b0 : l == 1 ? b1 : l == 2 ? b2 : b3;
            __builtin_nontemporal_store(b, out + t * 4 + l);
        }
    }
}

// ---- pre-pass 1: K fp32 -> bf16, 8 elems/thread, fully coalesced ----
__global__ void cast_k_kernel(const float* __restrict__ in, bf16* __restrict__ out) {
    size_t i = (size_t)blockIdx.x * blockDim.x + threadIdx.x;
    const float4* p = (const float4*)in + i * 2;
    float4 a = p[0], b = p[1];
    bf16x8 v;
    v[0]=(bf16)a.x; v[1]=(bf16)a.y; v[2]=(bf16)a.z; v[3]=(bf16)a.w;
    v[4]=(bf16)b.x; v[5]=(bf16)b.y; v[6]=(bf16)b.z; v[7]=(bf16)b.w;
    ((bf16x8*)out)[i] = v;
}

// ---- pre-pass 2: V fp32 [bh][s][d] -> bf16 Vt [bh][d][s] (LDS tile transpose) ----
__global__ void transpose_v_kernel(const float* __restrict__ V, bf16* __restrict__ Vt) {
    __shared__ float t[64][65];
    int bh = blockIdx.y;
    int s0 = blockIdx.x * 64;
    int tx = threadIdx.x & 63, ty = threadIdx.x >> 6;
    const float* vp = V + ((size_t)bh * SLEN + s0) * DH;
    #pragma unroll
    for (int r = ty; r < 64; r += 4) t[r][tx] = vp[(size_t)r * DH + tx];
    __syncthreads();
    bf16* op = Vt + (size_t)bh * DH * SLEN + s0;
    #pragma unroll
    for (int r = ty; r < 64; r += 4) op[(size_t)r * SLEN + tx] = (bf16)t[tx][r];
}

// ---- main attention kernel ----
// Block = 256 threads (4 waves), 64 q-rows per block (16/wave), k-tiles of 64.
// Swapped QK^T (S^T = mfma(K_frag, Q_frag)): lane (lq,lg) holds scores for
// q-row lq, k = n*16+lg*4+i. Mask arrives bit-packed: one 32 B load per lane
// per 256 k-cols. No online softmax needed: masked_fill is 0 (not -inf) and
// |s| <= ~7, so unnormalized exp is safe; divide by row-sum once at the end.
__global__ __launch_bounds__(256) void attn_kernel(
    const float* __restrict__ Q, const u64* __restrict__ pm,
    const bf16* __restrict__ Kb, const bf16* __restrict__ Vtb,
    float* __restrict__ out)
{
    __shared__ bf16 P_lds[64][72];   // pad 72: b128 reads tile all banks (verified R1)
    const int bh = blockIdx.y;
    const int qbase = blockIdx.x * 64;
    const int tid = threadIdx.x;
    const int w = tid >> 6, l = tid & 63;
    const int lq = l & 15, lg = l >> 4;

    // Q B-frags (col = lq(q), k = t*32 + lg*8 + j), hoisted; inline fp32->bf16
    bf16x8 aq[2];
    {
        const float* qp = Q + ((size_t)bh * SLEN + qbase + w * 16 + lq) * DH + lg * 8;
        #pragma unroll
        for (int t = 0; t < 2; ++t) {
            float4 x = *(const float4*)(qp + t * 32);
            float4 y = *(const float4*)(qp + t * 32 + 4);
            bf16x8 f;
            f[0]=(bf16)x.x; f[1]=(bf16)x.y; f[2]=(bf16)x.z; f[3]=(bf16)x.w;
            f[4]=(bf16)y.x; f[5]=(bf16)y.y; f[6]=(bf16)y.z; f[7]=(bf16)y.w;
            aq[t] = f;
        }
    }

    f32x4 acc[4] = {{0,0,0,0},{0,0,0,0},{0,0,0,0},{0,0,0,0}}; // ctx[16q][64d]
    float dpart = 0.f;                                        // partial denom, q=lq

    const bf16* kp = Kb  + (size_t)bh * SLEN * DH;
    const bf16* vp = Vtb + (size_t)bh * DH * SLEN;
    const u64*  pmrow = pm + ((size_t)bh * SLEN + qbase + w * 16 + lq) * 32; // 32 u64/row

    for (int g = 0; g < 8; ++g) {            // 8 groups of 256 k
        // 4 packed words for this lane's q-row covering k in [g*256, g*256+256)
        i32x4 wa = __builtin_nontemporal_load((const i32x4*)(pmrow + g * 4));
        i32x4 wb = __builtin_nontemporal_load((const i32x4*)(pmrow + g * 4 + 2));
        const unsigned lo[4] = {(unsigned)wa[0], (unsigned)wa[2], (unsigned)wb[0], (unsigned)wb[2]};
        const unsigned hi[4] = {(unsigned)wa[1], (unsigned)wa[3], (unsigned)wb[1], (unsigned)wb[3]};

        #pragma unroll
        for (int j = 0; j < 4; ++j) {        // 4 k-tiles of 64 per group
            const int kb = g * 256 + j * 64;

            // ---- S^T: 4 k-subtiles of 16, d=64 as 2 MFMAs each ----
            #pragma unroll
            for (int n = 0; n < 4; ++n) {
                f32x4 s = {0, 0, 0, 0};
                #pragma unroll
                for (int t = 0; t < 2; ++t) {
                    bf16x8 bk = *(const bf16x8*)(kp + (size_t)(kb + n * 16 + lq) * DH + t * 32 + lg * 8);
                    s = __builtin_amdgcn_mfma_f32_16x16x32_bf16(bk, aq[t], s, 0, 0, 0);
                }
                // mask bit for k = kb + n*16 + lg*4 + i lives in word i of this
                // group, bit (j*16 + n*4 + lg)  [j>=2 -> hi half]
                bf16x4 pk;
                #pragma unroll
                for (int i = 0; i < 4; ++i) {
                    unsigned u = (j & 2) ? hi[i] : lo[i];
                    unsigned bit = (u >> ((j & 1) * 16 + n * 4 + lg)) & 1u;
                    float e = bit ? 0.0f : s[i] * SCALE_LOG2E;
                    float p = exp2f(e);
                    dpart += p;
                    pk[i] = (bf16)p;
                }
                *(bf16x4*)(&P_lds[w * 16 + lq][n * 16 + lg * 4]) = pk;
            }

            // ---- PV: ctx += P(16x64) * V(64x64); same-wave LDS rows, no barrier ----
            #pragma unroll
            for (int n = 0; n < 4; ++n) {
                #pragma unroll
                for (int kk = 0; kk < 2; ++kk) {
                    bf16x8 ap = *(const bf16x8*)(&P_lds[w * 16 + lq][kk * 32 + lg * 8]);
                    bf16x8 bv = *(const bf16x8*)(vp + (size_t)(n * 16 + lq) * SLEN + kb + kk * 32 + lg * 8);
                    acc[n] = __builtin_amdgcn_mfma_f32_16x16x32_bf16(ap, bv, acc[n], 0, 0, 0);
                }
            }
        }
    }

    // denom: lanes {lq, lq+16, lq+32, lq+48} hold partials for q-row lq
    dpart += __shfl_xor(dpart, 16, 64);
    dpart += __shfl_xor(dpart, 32, 64);
    float dinv = 1.0f / dpart;

    // output rows are lg*4+i -> fetch matching 1/denom from lanes 0..15
    float di[4];
    #pragma unroll
    for (int i = 0; i < 4; ++i) di[i] = __shfl(dinv, lg * 4 + i, 64);

    float* op = out + ((size_t)bh * SLEN + qbase + w * 16) * DH;
    #pragma unroll
    for (int n = 0; n < 4; ++n) {
        #pragma unroll
        for (int i = 0; i < 4; ++i)
            op[(size_t)(lg * 4 + i) * DH + n * 16 + lq] = acc[n][i] * di[i];
    }
}

extern "C" void kernel_launch(void* const* d_in, const int* in_sizes, int n_in,
                              void* d_out, int out_size, void* d_ws, size_t ws_size,
                              hipStream_t stream) {
    const float* Q    = (const float*)d_in[0];
    const float* K    = (const float*)d_in[1];
    const float* V    = (const float*)d_in[2];
    const int*   mask = (const int*)d_in[3];
    float* out = (float*)d_out;

    // workspace: Kb (16 MB bf16) + Vt (16 MB bf16) + packed mask (33.5 MB)
    bf16* Kb  = (bf16*)d_ws;
    bf16* Vtb = Kb + (size_t)NBH * SLEN * DH;
    u64*  pmask = (u64*)(Vtb + (size_t)NBH * SLEN * DH);

    pack_mask_kernel<<<2048, 256, 0, stream>>>(mask, pmask);
    int n8 = NBH * SLEN * DH / 8;
    cast_k_kernel<<<n8 / 256, 256, 0, stream>>>(K, Kb);
    transpose_v_kernel<<<dim3(SLEN / 64, NBH), 256, 0, stream>>>(V, Vtb);
    attn_kernel<<<dim3(SLEN / 64, NBH), 256, 0, stream>>>(Q, pmask, Kb, Vtb, out);
}

// Round 4
// 371.619 us; speedup vs baseline: 1.8620x; 1.8620x over previous
//
#include <hip/hip_runtime.h>
#include <hip/hip_bf16.h>

typedef __bf16 bf16;
typedef __attribute__((ext_vector_type(8))) __bf16 bf16x8;
typedef __attribute__((ext_vector_type(4))) __bf16 bf16x4;
typedef __attribute__((ext_vector_type(4))) float f32x4;
typedef __attribute__((ext_vector_type(4))) int i32x4;

constexpr int SLEN = 2048;
constexpr int DH = 64;
constexpr int NBH = 64;                      // B*H = 4*16
constexpr float SCALE_LOG2E = 0.125f * 1.4426950408889634f;  // (1/sqrt(64)) * log2(e)

// ---- pre-pass 1: K fp32 -> bf16 row-major, 8 elems/thread ----
__global__ void cast_k_kernel(const float* __restrict__ in, bf16* __restrict__ out) {
    size_t i = (size_t)blockIdx.x * blockDim.x + threadIdx.x;
    const float4* p = (const float4*)in + i * 2;
    float4 a = p[0], b = p[1];
    bf16x8 v;
    v[0]=(bf16)a.x; v[1]=(bf16)a.y; v[2]=(bf16)a.z; v[3]=(bf16)a.w;
    v[4]=(bf16)b.x; v[5]=(bf16)b.y; v[6]=(bf16)b.z; v[7]=(bf16)b.w;
    ((bf16x8*)out)[i] = v;
}

// ---- pre-pass 2: V fp32 [bh][s][d] -> bf16 Vt [bh][d][s] ----
__global__ void transpose_v_kernel(const float* __restrict__ V, bf16* __restrict__ Vt) {
    __shared__ float t[64][65];
    int bh = blockIdx.y;
    int s0 = blockIdx.x * 64;
    int tx = threadIdx.x & 63, ty = threadIdx.x >> 6;
    const float* vp = V + ((size_t)bh * SLEN + s0) * DH;
    #pragma unroll
    for (int r = ty; r < 64; r += 4) t[r][tx] = vp[(size_t)r * DH + tx];
    __syncthreads();
    bf16* op = Vt + (size_t)bh * DH * SLEN + s0;
    #pragma unroll
    for (int r = ty; r < 64; r += 4) op[(size_t)r * SLEN + tx] = (bf16)t[tx][r];
}

// async global->LDS, 16B per lane, dest = wave-uniform base + lane*16
__device__ __forceinline__ void gl_lds16(const void* g, void* l) {
    __builtin_amdgcn_global_load_lds(
        (const __attribute__((address_space(1))) void*)g,
        (__attribute__((address_space(3))) void*)l, 16, 0, 0);
}

// ---- main attention kernel ----
// 4 waves, 64 q-rows/block, k-tiles of 64, double-buffered LDS staging of
// {K-tile 8KB, Vt-tile 8KB, mask-tile 16KB} via global_load_lds (2-phase
// schedule: STAGE(t+1) issued before COMPUTE(t), one barrier per tile).
// K/V LDS rows (128B) swizzled byte^=(row&7)<<4; mask rows (256B) swizzled
// byte^=(row&15)<<4 — swizzle applied on the GLOBAL SOURCE side (linear LDS
// dest) and mirrored on reads.
// Swapped QK^T: lane (lq,lg) holds scores for q-row lq, k=n*16+lg*4+i.
// masked_fill is 0 (not -inf), |s|<=~7 -> unnormalized exp is safe.
__global__ __launch_bounds__(256) void attn_kernel(
    const float* __restrict__ Q, const int* __restrict__ mask,
    const bf16* __restrict__ Kb, const bf16* __restrict__ Vtb,
    float* __restrict__ out)
{
    __shared__ char KT[2][8192];
    __shared__ char VT[2][8192];
    __shared__ char MT[2][16384];
    __shared__ bf16 P_lds[64][72];

    const int bh = blockIdx.y;
    const int qbase = blockIdx.x * 64;
    const int tid = threadIdx.x;
    const int w = tid >> 6, l = tid & 63;
    const int lq = l & 15, lg = l >> 4;

    const char* kgb = (const char*)(Kb + (size_t)bh * SLEN * DH);      // rows 128B
    const char* vgb = (const char*)(Vtb + (size_t)bh * DH * SLEN);     // rows 4096B
    const char* mgb = (const char*)(mask + ((size_t)bh * SLEN + qbase) * SLEN); // rows 8192B

    // loop-invariant per-lane staging geometry
    const int kv_r = l >> 3;                             // row-in-octet 0..7
    const int kv_c = ((l & 7) * 16) ^ (kv_r << 4);       // swizzled col byte (K/V)

    // Q B-frags (q-col = lq, k = t*32+lg*8+j), hoisted fp32->bf16
    bf16x8 aq[2];
    {
        const float* qp = Q + ((size_t)bh * SLEN + qbase + w * 16 + lq) * DH + lg * 8;
        #pragma unroll
        for (int t = 0; t < 2; ++t) {
            float4 x = *(const float4*)(qp + t * 32);
            float4 y = *(const float4*)(qp + t * 32 + 4);
            bf16x8 f;
            f[0]=(bf16)x.x; f[1]=(bf16)x.y; f[2]=(bf16)x.z; f[3]=(bf16)x.w;
            f[4]=(bf16)y.x; f[5]=(bf16)y.y; f[6]=(bf16)y.z; f[7]=(bf16)y.w;
            aq[t] = f;
        }
    }

    f32x4 acc[4] = {{0,0,0,0},{0,0,0,0},{0,0,0,0},{0,0,0,0}};
    float dpart = 0.f;
    const int swzk = (lq & 7) << 4;

    // ---- staging: 8 global_load_lds per wave per tile (2 K + 2 V + 4 M) ----
    auto stage = [&](int kb, int buf) {
        #pragma unroll
        for (int q = 0; q < 2; ++q) {
            int r = (w * 2 + q) * 8 + kv_r;              // tile row 0..63
            gl_lds16(kgb + (size_t)(kb + r) * 128 + kv_c,
                     &KT[buf][(w * 2 + q) * 1024]);
            gl_lds16(vgb + (size_t)r * 4096 + (size_t)kb * 2 + kv_c,
                     &VT[buf][(w * 2 + q) * 1024]);
        }
        #pragma unroll
        for (int q = 0; q < 4; ++q) {
            int r = (w * 4 + q) * 4 + (l >> 4);          // q-row 0..63
            int c = ((l & 15) * 16) ^ ((r & 15) << 4);   // swizzled col byte (M)
            gl_lds16(mgb + (size_t)r * 8192 + (size_t)kb * 4 + c,
                     &MT[buf][(w * 4 + q) * 1024]);
        }
    };

    stage(0, 0);
    __syncthreads();   // drains vmcnt -> buf0 ready

    int cur = 0;
    for (int kt = 0; kt < SLEN / 64; ++kt) {
        if (kt + 1 < SLEN / 64) stage((kt + 1) * 64, cur ^ 1);   // prefetch first

        // ---- QK^T from LDS K + mask + exp + stage P (same-wave rows) ----
        #pragma unroll
        for (int n = 0; n < 4; ++n) {
            f32x4 s = {0, 0, 0, 0};
            #pragma unroll
            for (int t = 0; t < 2; ++t) {
                bf16x8 bk = *(const bf16x8*)&KT[cur][(n * 16 + lq) * 128 + ((t * 64 + lg * 16) ^ swzk)];
                s = __builtin_amdgcn_mfma_f32_16x16x32_bf16(bk, aq[t], s, 0, 0, 0);
            }
            i32x4 mv = *(const i32x4*)&MT[cur][(w * 16 + lq) * 256 + ((n * 64 + lg * 16) ^ (lq << 4))];
            bf16x4 pk;
            #pragma unroll
            for (int i = 0; i < 4; ++i) {
                float e = mv[i] ? 0.0f : s[i] * SCALE_LOG2E;
                float p = exp2f(e);
                dpart += p;
                pk[i] = (bf16)p;
            }
            *(bf16x4*)(&P_lds[w * 16 + lq][n * 16 + lg * 4]) = pk;
        }

        // ---- PV from LDS V; P rows are wave-private (no barrier needed) ----
        #pragma unroll
        for (int n = 0; n < 4; ++n) {
            #pragma unroll
            for (int kk = 0; kk < 2; ++kk) {
                bf16x8 ap = *(const bf16x8*)(&P_lds[w * 16 + lq][kk * 32 + lg * 8]);
                bf16x8 bv = *(const bf16x8*)&VT[cur][(n * 16 + lq) * 128 + ((kk * 64 + lg * 16) ^ swzk)];
                acc[n] = __builtin_amdgcn_mfma_f32_16x16x32_bf16(ap, bv, acc[n], 0, 0, 0);
            }
        }

        __syncthreads();   // next-tile staging complete + all reads of cur done
        cur ^= 1;
    }

    // denom: lanes {lq, lq+16, lq+32, lq+48} hold partials for q-row lq
    dpart += __shfl_xor(dpart, 16, 64);
    dpart += __shfl_xor(dpart, 32, 64);
    float dinv = 1.0f / dpart;

    float di[4];
    #pragma unroll
    for (int i = 0; i < 4; ++i) di[i] = __shfl(dinv, lg * 4 + i, 64);

    float* op = out + ((size_t)bh * SLEN + qbase + w * 16) * DH;
    #pragma unroll
    for (int n = 0; n < 4; ++n) {
        #pragma unroll
        for (int i = 0; i < 4; ++i)
            op[(size_t)(lg * 4 + i) * DH + n * 16 + lq] = acc[n][i] * di[i];
    }
}

extern "C" void kernel_launch(void* const* d_in, const int* in_sizes, int n_in,
                              void* d_out, int out_size, void* d_ws, size_t ws_size,
                              hipStream_t stream) {
    const float* Q    = (const float*)d_in[0];
    const float* K    = (const float*)d_in[1];
    const float* V    = (const float*)d_in[2];
    const int*   mask = (const int*)d_in[3];
    float* out = (float*)d_out;

    bf16* Kb  = (bf16*)d_ws;                       // 16 MB
    bf16* Vtb = Kb + (size_t)NBH * SLEN * DH;      // 16 MB

    int n8 = NBH * SLEN * DH / 8;
    cast_k_kernel<<<n8 / 256, 256, 0, stream>>>(K, Kb);
    transpose_v_kernel<<<dim3(SLEN / 64, NBH), 256, 0, stream>>>(V, Vtb);
    attn_kernel<<<dim3(SLEN / 64, NBH), 256, 0, stream>>>(Q, mask, Kb, Vtb, out);
}

// Round 5
// 323.210 us; speedup vs baseline: 2.1408x; 1.1498x over previous
//
#include <hip/hip_runtime.h>
#include <hip/hip_bf16.h>

typedef __bf16 bf16;
typedef __attribute__((ext_vector_type(8))) __bf16 bf16x8;
typedef __attribute__((ext_vector_type(4))) __bf16 bf16x4;
typedef __attribute__((ext_vector_type(4))) float f32x4;
typedef __attribute__((ext_vector_type(4))) int i32x4;

constexpr int SLEN = 2048;
constexpr int DH = 64;
constexpr int NBH = 64;                      // B*H = 4*16
constexpr float SCALE_LOG2E = 0.125f * 1.4426950408889634f;  // (1/sqrt(64)) * log2(e)

// ---- pre-pass 1: K fp32 -> bf16 row-major, 8 elems/thread ----
__global__ void cast_k_kernel(const float* __restrict__ in, bf16* __restrict__ out) {
    size_t i = (size_t)blockIdx.x * blockDim.x + threadIdx.x;
    const float4* p = (const float4*)in + i * 2;
    float4 a = p[0], b = p[1];
    bf16x8 v;
    v[0]=(bf16)a.x; v[1]=(bf16)a.y; v[2]=(bf16)a.z; v[3]=(bf16)a.w;
    v[4]=(bf16)b.x; v[5]=(bf16)b.y; v[6]=(bf16)b.z; v[7]=(bf16)b.w;
    ((bf16x8*)out)[i] = v;
}

// ---- pre-pass 2: V fp32 [bh][s][d] -> bf16 Vt [bh][d][s] ----
__global__ void transpose_v_kernel(const float* __restrict__ V, bf16* __restrict__ Vt) {
    __shared__ float t[64][65];
    int bh = blockIdx.y;
    int s0 = blockIdx.x * 64;
    int tx = threadIdx.x & 63, ty = threadIdx.x >> 6;
    const float* vp = V + ((size_t)bh * SLEN + s0) * DH;
    #pragma unroll
    for (int r = ty; r < 64; r += 4) t[r][tx] = vp[(size_t)r * DH + tx];
    __syncthreads();
    bf16* op = Vt + (size_t)bh * DH * SLEN + s0;
    #pragma unroll
    for (int r = ty; r < 64; r += 4) op[(size_t)r * SLEN + tx] = (bf16)t[tx][r];
}

// async global->LDS, 16B per lane, dest = wave-uniform base + lane*16
__device__ __forceinline__ void gl_lds16(const void* g, void* l) {
    __builtin_amdgcn_global_load_lds(
        (const __attribute__((address_space(1))) void*)g,
        (__attribute__((address_space(3))) void*)l, 16, 0, 0);
}

// ---- main attention kernel ----
// 4 waves, 64 q-rows/block, k-tiles of 64. K/Vt tiles double-buffered in LDS
// via global_load_lds (2-phase: STAGE(t+1) before COMPUTE(t), one barrier per
// tile), rows XOR-swizzled byte^=(row&7)<<4 applied on the GLOBAL SOURCE side
// (linear LDS dest) and mirrored on reads. Mask (single-use) bypasses LDS:
// direct i32x4 nontemporal loads double-buffered one tile ahead in registers.
// P tile: flat 8KB, same XOR swizzle (bank-optimal for b64 write + b128 read).
// LDS total 40KB -> 4 blocks/CU.
// Swapped QK^T: lane (lq,lg) holds scores for q-row lq, k=n*16+lg*4+i.
// masked_fill is 0 (not -inf), |s|<=~7 -> unnormalized exp safe; one divide.
__global__ __launch_bounds__(256, 4) void attn_kernel(
    const float* __restrict__ Q, const int* __restrict__ mask,
    const bf16* __restrict__ Kb, const bf16* __restrict__ Vtb,
    float* __restrict__ out)
{
    __shared__ char KT[2][8192];
    __shared__ char VT[2][8192];
    __shared__ char PT[8192];

    const int bh = blockIdx.y;
    const int qbase = blockIdx.x * 64;
    const int tid = threadIdx.x;
    const int w = tid >> 6, l = tid & 63;
    const int lq = l & 15, lg = l >> 4;

    const char* kgb = (const char*)(Kb + (size_t)bh * SLEN * DH);      // rows 128B
    const char* vgb = (const char*)(Vtb + (size_t)bh * DH * SLEN);     // rows 4096B

    // staging geometry: lane covers (row octet kv_r, swizzled 16B col kv_c)
    const int kv_r = l >> 3;                             // 0..7
    const int kv_c = ((l & 7) * 16) ^ (kv_r << 4);

    // Q B-frags (q-col = lq, k = t*32+lg*8+j), hoisted fp32->bf16
    bf16x8 aq[2];
    {
        const float* qp = Q + ((size_t)bh * SLEN + qbase + w * 16 + lq) * DH + lg * 8;
        #pragma unroll
        for (int t = 0; t < 2; ++t) {
            float4 x = *(const float4*)(qp + t * 32);
            float4 y = *(const float4*)(qp + t * 32 + 4);
            bf16x8 f;
            f[0]=(bf16)x.x; f[1]=(bf16)x.y; f[2]=(bf16)x.z; f[3]=(bf16)x.w;
            f[4]=(bf16)y.x; f[5]=(bf16)y.y; f[6]=(bf16)y.z; f[7]=(bf16)y.w;
            aq[t] = f;
        }
    }

    f32x4 acc[4] = {{0,0,0,0},{0,0,0,0},{0,0,0,0},{0,0,0,0}};
    float dpart = 0.f;
    const int swzk = (lq & 7) << 4;      // read-side XOR (row&7)<<4, row%8==lq%8
    const int prow = w * 16 + lq;
    char* pb = PT + prow * 128;
    const int pswz = (prow & 7) << 4;

    // K/V staging: 4 global_load_lds per wave per tile (2 K + 2 V)
    auto stage = [&](int kb, int buf) {
        #pragma unroll
        for (int q = 0; q < 2; ++q) {
            int r = (w * 2 + q) * 8 + kv_r;              // tile row 0..63
            gl_lds16(kgb + (size_t)(kb + r) * 128 + kv_c, &KT[buf][(w * 2 + q) * 1024]);
            gl_lds16(vgb + (size_t)r * 4096 + (size_t)kb * 2 + kv_c, &VT[buf][(w * 2 + q) * 1024]);
        }
    };

    // mask: direct per-lane loads for q-row (qbase+w*16+lq), 1 tile ahead
    const int* mrow = mask + ((size_t)bh * SLEN + qbase + w * 16 + lq) * SLEN;
    i32x4 mcur[4], mnext[4];
    #pragma unroll
    for (int n = 0; n < 4; ++n)
        mcur[n] = __builtin_nontemporal_load((const i32x4*)(mrow + n * 16 + lg * 4));

    stage(0, 0);
    __syncthreads();   // drains vmcnt -> buf0 ready

    int cur = 0;
    for (int kt = 0; kt < SLEN / 64; ++kt) {
        const bool has_next = (kt + 1) < (SLEN / 64);    // wave-uniform
        if (has_next) {
            stage((kt + 1) * 64, cur ^ 1);               // K/V prefetch first
            #pragma unroll
            for (int n = 0; n < 4; ++n)
                mnext[n] = __builtin_nontemporal_load(
                    (const i32x4*)(mrow + (kt + 1) * 64 + n * 16 + lg * 4));
        }

        // ---- QK^T from LDS K + mask + exp + stage P (same-wave rows) ----
        #pragma unroll
        for (int n = 0; n < 4; ++n) {
            f32x4 s = {0, 0, 0, 0};
            #pragma unroll
            for (int t = 0; t < 2; ++t) {
                bf16x8 bk = *(const bf16x8*)&KT[cur][(n * 16 + lq) * 128 + ((t * 64 + lg * 16) ^ swzk)];
                s = __builtin_amdgcn_mfma_f32_16x16x32_bf16(bk, aq[t], s, 0, 0, 0);
            }
            bf16x4 pk;
            #pragma unroll
            for (int i = 0; i < 4; ++i) {
                float e = mcur[n][i] ? 0.0f : s[i] * SCALE_LOG2E;
                float p = exp2f(e);
                dpart += p;
                pk[i] = (bf16)p;
            }
            *(bf16x4*)(pb + ((n * 32 + lg * 8) ^ pswz)) = pk;
        }

        // ---- PV from LDS V; P rows are wave-private (no barrier needed) ----
        #pragma unroll
        for (int n = 0; n < 4; ++n) {
            #pragma unroll
            for (int kk = 0; kk < 2; ++kk) {
                bf16x8 ap = *(const bf16x8*)(pb + ((kk * 64 + lg * 16) ^ pswz));
                bf16x8 bv = *(const bf16x8*)&VT[cur][(n * 16 + lq) * 128 + ((kk * 64 + lg * 16) ^ swzk)];
                acc[n] = __builtin_amdgcn_mfma_f32_16x16x32_bf16(ap, bv, acc[n], 0, 0, 0);
            }
        }

        if (has_next) {
            #pragma unroll
            for (int n = 0; n < 4; ++n) mcur[n] = mnext[n];
        }
        __syncthreads();   // next-tile staging complete + all reads of cur done
        cur ^= 1;
    }

    // denom: lanes {lq, lq+16, lq+32, lq+48} hold partials for q-row lq
    dpart += __shfl_xor(dpart, 16, 64);
    dpart += __shfl_xor(dpart, 32, 64);
    float dinv = 1.0f / dpart;

    float di[4];
    #pragma unroll
    for (int i = 0; i < 4; ++i) di[i] = __shfl(dinv, lg * 4 + i, 64);

    float* op = out + ((size_t)bh * SLEN + qbase + w * 16) * DH;
    #pragma unroll
    for (int n = 0; n < 4; ++n) {
        #pragma unroll
        for (int i = 0; i < 4; ++i)
            op[(size_t)(lg * 4 + i) * DH + n * 16 + lq] = acc[n][i] * di[i];
    }
}

extern "C" void kernel_launch(void* const* d_in, const int* in_sizes, int n_in,
                              void* d_out, int out_size, void* d_ws, size_t ws_size,
                              hipStream_t stream) {
    const float* Q    = (const float*)d_in[0];
    const float* K    = (const float*)d_in[1];
    const float* V    = (const float*)d_in[2];
    const int*   mask = (const int*)d_in[3];
    float* out = (float*)d_out;

    bf16* Kb  = (bf16*)d_ws;                       // 16 MB
    bf16* Vtb = Kb + (size_t)NBH * SLEN * DH;      // 16 MB

    int n8 = NBH * SLEN * DH / 8;
    cast_k_kernel<<<n8 / 256, 256, 0, stream>>>(K, Kb);
    transpose_v_kernel<<<dim3(SLEN / 64, NBH), 256, 0, stream>>>(V, Vtb);
    attn_kernel<<<dim3(SLEN / 64, NBH), 256, 0, stream>>>(Q, mask, Kb, Vtb, out);
}

// Round 8
// 312.349 us; speedup vs baseline: 2.2153x; 1.0348x over previous
//
#include <hip/hip_runtime.h>
#include <hip/hip_bf16.h>

typedef __bf16 bf16;
typedef __attribute__((ext_vector_type(8))) __bf16 bf16x8;
typedef __attribute__((ext_vector_type(4))) __bf16 bf16x4;
typedef __attribute__((ext_vector_type(4))) float f32x4;
typedef __attribute__((ext_vector_type(4))) int i32x4;

constexpr int SLEN = 2048;
constexpr int DH = 64;
constexpr int NBH = 64;                      // B*H = 4*16
constexpr float SCALE_LOG2E = 0.125f * 1.4426950408889634f;  // (1/sqrt(64)) * log2(e)

// ---- fused pre-pass: K fp32->bf16 (coalesced) + V fp32 [s][d] -> bf16 Vt [d][s] ----
__global__ __launch_bounds__(256) void prep_kv_kernel(
    const float* __restrict__ K, const float* __restrict__ V,
    bf16* __restrict__ Kb, bf16* __restrict__ Vt)
{
    __shared__ float t[64][65];
    const int bh = blockIdx.y;
    const int s0 = blockIdx.x * 64;
    const int tx = threadIdx.x & 63, ty = threadIdx.x >> 6;

    // V tile -> LDS
    const float* vp = V + ((size_t)bh * SLEN + s0) * DH;
    #pragma unroll
    for (int r = ty; r < 64; r += 4) t[r][tx] = vp[(size_t)r * DH + tx];

    // K cast (independent of LDS; overlaps the transpose latency)
    {
        const float* kp = K + ((size_t)bh * SLEN + s0) * DH;
        bf16* kbp = Kb + ((size_t)bh * SLEN + s0) * DH;
        int r = threadIdx.x >> 2, c = (threadIdx.x & 3) * 16;
        const float4* src = (const float4*)(kp + (size_t)r * DH + c);
        float4 a = src[0], b = src[1], c2 = src[2], d = src[3];
        bf16x8 o0, o1;
        o0[0]=(bf16)a.x;  o0[1]=(bf16)a.y;  o0[2]=(bf16)a.z;  o0[3]=(bf16)a.w;
        o0[4]=(bf16)b.x;  o0[5]=(bf16)b.y;  o0[6]=(bf16)b.z;  o0[7]=(bf16)b.w;
        o1[0]=(bf16)c2.x; o1[1]=(bf16)c2.y; o1[2]=(bf16)c2.z; o1[3]=(bf16)c2.w;
        o1[4]=(bf16)d.x;  o1[5]=(bf16)d.y;  o1[6]=(bf16)d.z;  o1[7]=(bf16)d.w;
        *(bf16x8*)(kbp + (size_t)r * DH + c)     = o0;
        *(bf16x8*)(kbp + (size_t)r * DH + c + 8) = o1;
    }

    __syncthreads();
    bf16* op = Vt + (size_t)bh * DH * SLEN + s0;
    #pragma unroll
    for (int r = ty; r < 64; r += 4) op[(size_t)r * SLEN + tx] = (bf16)t[tx][r];
}

// async global->LDS, 16B per lane, dest = wave-uniform base + lane*16
__device__ __forceinline__ void gl_lds16(const void* g, void* l) {
    __builtin_amdgcn_global_load_lds(
        (const __attribute__((address_space(1))) void*)g,
        (__attribute__((address_space(3))) void*)l, 16, 0, 0);
}

// ---- main attention kernel ----
// 4 waves, 64 q-rows/block, k-tiles of 64, tile t uses LDS buf (t&1).
// T4 counted-vmcnt schedule: per tile issue {4 gl_lds (K/V), then 4 mask
// loads}; end-of-tile sync = s_waitcnt vmcnt(4) lgkmcnt(0) + s_barrier:
// gl_lds retired, this wave's DS pipe drained (raw s_barrier implies no
// waits!), mask loads stay in flight across the barrier and are consumed
// (register ping-pong mA/mB, statically indexed) next tile.
// R6/R7 bug fixed here: stage() took an ELEMENT offset but was passed the
// TILE INDEX (stage(kt+1) instead of stage((kt+1)*64)) -> all K/V tiles after
// the prologue came from wrong addresses, deterministic absmax 2.5. stage()
// now takes the tile index and converts internally (same contract as
// loadmask), eliminating the units mismatch.
// K/V LDS rows swizzled byte^=(row&7)<<4 on the GLOBAL SOURCE side (linear
// LDS dest), mirrored on reads. P tile flat 8KB, same swizzle. LDS 40KB ->
// 4 blocks/CU. XCD-bijective block swizzle locks each bh's 32 blocks to one
// XCD so K/V are fetched from HBM once per device, not once per XCD.
// Swapped QK^T: lane (lq,lg) holds scores for q-row lq, k=n*16+lg*4+i.
// masked_fill is 0 (not -inf), |s|<=~7 -> unnormalized exp safe; one divide.
__global__ __launch_bounds__(256, 4) void attn_kernel(
    const float* __restrict__ Q, const int* __restrict__ mask,
    const bf16* __restrict__ Kb, const bf16* __restrict__ Vtb,
    float* __restrict__ out)
{
    __shared__ char KT[2][8192];
    __shared__ char VT[2][8192];
    __shared__ char PT[8192];

    // XCD-aware bijective swizzle (2048 blocks, 2048%8==0): XCD x owns bh 8x..8x+7
    const int h = blockIdx.x;
    const int logical = (h & 7) * 256 + (h >> 3);
    const int bh = logical >> 5;
    const int qbase = (logical & 31) * 64;
    const int tid = threadIdx.x;
    const int w = tid >> 6, l = tid & 63;
    const int lq = l & 15, lg = l >> 4;

    const char* kgb = (const char*)(Kb + (size_t)bh * SLEN * DH);      // rows 128B
    const char* vgb = (const char*)(Vtb + (size_t)bh * DH * SLEN);     // rows 4096B

    // staging geometry: lane covers (row octet kv_r, swizzled 16B col kv_c)
    const int kv_r = l >> 3;                             // 0..7
    const int kv_c = ((l & 7) * 16) ^ (kv_r << 4);

    // Q B-frags (q-col = lq, k = t*32+lg*8+j), hoisted fp32->bf16
    bf16x8 aq[2];
    {
        const float* qp = Q + ((size_t)bh * SLEN + qbase + w * 16 + lq) * DH + lg * 8;
        #pragma unroll
        for (int t = 0; t < 2; ++t) {
            float4 x = *(const float4*)(qp + t * 32);
            float4 y = *(const float4*)(qp + t * 32 + 4);
            bf16x8 f;
            f[0]=(bf16)x.x; f[1]=(bf16)x.y; f[2]=(bf16)x.z; f[3]=(bf16)x.w;
            f[4]=(bf16)y.x; f[5]=(bf16)y.y; f[6]=(bf16)y.z; f[7]=(bf16)y.w;
            aq[t] = f;
        }
    }

    f32x4 acc[4] = {{0,0,0,0},{0,0,0,0},{0,0,0,0},{0,0,0,0}};
    float dpart = 0.f;
    const int swzk = (lq & 7) << 4;      // read-side XOR, row%8 == lq%8
    const int prow = w * 16 + lq;
    char* pb = PT + prow * 128;
    const int pswz = (prow & 7) << 4;

    const int* mrow = mask + ((size_t)bh * SLEN + qbase + w * 16 + lq) * SLEN;

    // K/V staging for k-tile index t: 4 gl_lds per wave (2 K + 2 V)
    auto stage = [&](int t, int buf) {
        const int kb = t * 64;                           // element offset
        #pragma unroll
        for (int q = 0; q < 2; ++q) {
            int r = (w * 2 + q) * 8 + kv_r;              // tile row 0..63
            gl_lds16(kgb + (size_t)(kb + r) * 128 + kv_c, &KT[buf][(w * 2 + q) * 1024]);
            gl_lds16(vgb + (size_t)r * 4096 + (size_t)kb * 2 + kv_c, &VT[buf][(w * 2 + q) * 1024]);
        }
    };
    auto loadmask = [&](int t, i32x4* m) {
        #pragma unroll
        for (int n = 0; n < 4; ++n)
            m[n] = __builtin_nontemporal_load((const i32x4*)(mrow + t * 64 + n * 16 + lg * 4));
    };
    // one k-tile of compute, reading LDS buf `cur` and mask regs mC
    auto body = [&](int cur, const i32x4* mC) {
        #pragma unroll
        for (int n = 0; n < 4; ++n) {
            f32x4 s = {0, 0, 0, 0};
            #pragma unroll
            for (int t = 0; t < 2; ++t) {
                bf16x8 bk = *(const bf16x8*)&KT[cur][(n * 16 + lq) * 128 + ((t * 64 + lg * 16) ^ swzk)];
                s = __builtin_amdgcn_mfma_f32_16x16x32_bf16(bk, aq[t], s, 0, 0, 0);
            }
            bf16x4 pk;
            #pragma unroll
            for (int i = 0; i < 4; ++i) {
                float e = mC[n][i] ? 0.0f : s[i] * SCALE_LOG2E;
                float p = exp2f(e);
                dpart += p;
                pk[i] = (bf16)p;
            }
            *(bf16x4*)(pb + ((n * 32 + lg * 8) ^ pswz)) = pk;
        }
        #pragma unroll
        for (int n = 0; n < 4; ++n) {
            #pragma unroll
            for (int kk = 0; kk < 2; ++kk) {
                bf16x8 ap = *(const bf16x8*)(pb + ((kk * 64 + lg * 16) ^ pswz));
                bf16x8 bv = *(const bf16x8*)&VT[cur][(n * 16 + lq) * 128 + ((kk * 64 + lg * 16) ^ swzk)];
                acc[n] = __builtin_amdgcn_mfma_f32_16x16x32_bf16(ap, bv, acc[n], 0, 0, 0);
            }
        }
    };
    // counted sync: gl_lds (older) retired, DS pipe drained; 4 mask loads
    // (newest) stay in flight across the barrier.
    auto tile_sync = [&]() {
        asm volatile("s_waitcnt vmcnt(4) lgkmcnt(0)" ::: "memory");
        __builtin_amdgcn_s_barrier();
        __builtin_amdgcn_sched_barrier(0);
    };

    i32x4 mA[4], mB[4];

    // prologue: tile 0 -> buf0, mask0 -> mA
    stage(0, 0);
    __builtin_amdgcn_sched_barrier(0);   // keep mask loads newer than gl_lds
    loadmask(0, mA);
    tile_sync();

    for (int kt = 0; kt < SLEN / 64; kt += 2) {
        // even tile kt: reads buf0/mA; prefetch tile kt+1 -> buf1/mB
        stage(kt + 1, 1);
        __builtin_amdgcn_sched_barrier(0);
        loadmask(kt + 1, mB);
        body(0, mA);
        tile_sync();

        // odd tile kt+1: reads buf1/mB; prefetch tile kt+2 -> buf0/mA
        const bool more = (kt + 2) < (SLEN / 64);
        if (more) {
            stage(kt + 2, 0);
            __builtin_amdgcn_sched_barrier(0);
            loadmask(kt + 2, mA);
        }
        body(1, mB);
        if (more) tile_sync();
    }

    // denom: lanes {lq, lq+16, lq+32, lq+48} hold partials for q-row lq
    dpart += __shfl_xor(dpart, 16, 64);
    dpart += __shfl_xor(dpart, 32, 64);
    float dinv = 1.0f / dpart;

    float di[4];
    #pragma unroll
    for (int i = 0; i < 4; ++i) di[i] = __shfl(dinv, lg * 4 + i, 64);

    float* op = out + ((size_t)bh * SLEN + qbase + w * 16) * DH;
    #pragma unroll
    for (int n = 0; n < 4; ++n) {
        #pragma unroll
        for (int i = 0; i < 4; ++i)
            op[(size_t)(lg * 4 + i) * DH + n * 16 + lq] = acc[n][i] * di[i];
    }
}

extern "C" void kernel_launch(void* const* d_in, const int* in_sizes, int n_in,
                              void* d_out, int out_size, void* d_ws, size_t ws_size,
                              hipStream_t stream) {
    const float* Q    = (const float*)d_in[0];
    const float* K    = (const float*)d_in[1];
    const float* V    = (const float*)d_in[2];
    const int*   mask = (const int*)d_in[3];
    float* out = (float*)d_out;

    bf16* Kb  = (bf16*)d_ws;                       // 16 MB
    bf16* Vtb = Kb + (size_t)NBH * SLEN * DH;      // 16 MB

    prep_kv_kernel<<<dim3(SLEN / 64, NBH), 256, 0, stream>>>(K, V, Kb, Vtb);
    attn_kernel<<<2048, 256, 0, stream>>>(Q, mask, Kb, Vtb, out);
}